// Round 2
// baseline (6284.608 us; speedup 1.0000x reference)
//
#include <hip/hip_runtime.h>

// TrajectoryDecoder: 2-layer LSTM (H=256), 45 steps, B=4096, fp32.
// One WG (256 thr) owns BB=16 batch elements for the whole rollout.
// Thread t owns hidden unit u=t: gate rows {u, u+256, u+512, u+768},
// c-state in registers, h-state in LDS (uniform broadcast reads).
// Weights streamed from L2 (3.15 MB/step/WG, shared across all CUs).

#define BB     16
#define TPB    256
#define HN     256
#define DM     128
#define NSTEP  45

__device__ __forceinline__ float sigm(float x){
  x = fminf(40.f, fmaxf(-40.f, x));
  return 1.f/(1.f + __expf(-x));
}
__device__ __forceinline__ float tanhx(float x){
  float xx = fminf(15.f, fmaxf(-15.f, x));
  float e = __expf(2.f*xx);
  return (e-1.f)/(e+1.f);
}

// acc[4][BB] must be in scope. WRP: array of 4 row pointers (float4*), HSH: LDS [BB][HN].
#define MATVEC(WRP, HSH) do{ \
  float4 cw[8], nw[8]; \
  _Pragma("unroll") for (int g=0; g<4; g++){ cw[2*g]=WRP[g][0]; cw[2*g+1]=WRP[g][1]; } \
  _Pragma("nounroll") \
  for (int kk=0; kk<HN/8; kk++){ \
    if (kk < HN/8-1){ \
      _Pragma("unroll") for (int g=0; g<4; g++){ nw[2*g]=WRP[g][2*kk+2]; nw[2*g+1]=WRP[g][2*kk+3]; } \
    } \
    _Pragma("unroll") for (int b=0; b<BB; b++){ \
      float4 ha = *(const float4*)&HSH[b][kk*8]; \
      float4 hb = *(const float4*)&HSH[b][kk*8+4]; \
      _Pragma("unroll") for (int g=0; g<4; g++){ \
        acc[g][b] += cw[2*g].x*ha.x + cw[2*g].y*ha.y + cw[2*g].z*ha.z + cw[2*g].w*ha.w \
                   + cw[2*g+1].x*hb.x + cw[2*g+1].y*hb.y + cw[2*g+1].z*hb.z + cw[2*g+1].w*hb.w; \
      } \
    } \
    if (kk < HN/8-1){ _Pragma("unroll") for (int q=0;q<8;q++) cw[q]=nw[q]; } \
  } \
}while(0)

__global__ __launch_bounds__(TPB, 1)
void traj_kernel(const float* __restrict__ enc,   // B x 128
                 const float* __restrict__ pos0,  // B x 2
                 const float* __restrict__ ctx,   // B x 128
                 const float* __restrict__ Wh,    // 512 x 128
                 const float* __restrict__ bh,    // 512
                 const float* __restrict__ Wc,    // 512 x 128
                 const float* __restrict__ bc,    // 512
                 const float* __restrict__ Wih0,  // 1024 x 130
                 const float* __restrict__ Whh0,  // 1024 x 256
                 const float* __restrict__ bih0,
                 const float* __restrict__ bhh0,
                 const float* __restrict__ Wih1,  // 1024 x 256
                 const float* __restrict__ Whh1,  // 1024 x 256
                 const float* __restrict__ bih1,
                 const float* __restrict__ bhh1,
                 const float* __restrict__ Wp1,   // 64 x 256
                 const float* __restrict__ bp1,   // 64
                 const float* __restrict__ Wp2,   // 2 x 64
                 const float* __restrict__ bp2,   // 2
                 float* __restrict__ out)         // B x 45 x 2
{
  __shared__ float sh_h0[BB][HN];      // 16 KB
  __shared__ float sh_h1[BB][HN];      // 16 KB
  __shared__ float sh_gctx[BB][1024];  // 64 KB (per-step constant gates_x from context)
  __shared__ float sh_x[BB][DM];       // 8 KB staging
  __shared__ float sh_pos[BB][2];

  const int tid = threadIdx.x;
  const int u   = tid;                 // owned hidden unit
  const int gb0 = blockIdx.x * BB;     // global batch base

  // ---- stage encoder_feat tile ----
  {
    const float4* src = (const float4*)(enc + (size_t)gb0*DM);
    float4* dst = (float4*)&sh_x[0][0];
    #pragma unroll
    for (int i=0;i<(BB*DM/4)/TPB;i++) dst[tid + i*TPB] = src[tid + i*TPB];
  }
  if (tid < BB*2) ((float*)sh_pos)[tid] = pos0[(size_t)gb0*2 + tid];
  __syncthreads();

  float c0r[BB], c1r[BB];

  // ---- h/c init: h_all = enc @ Wh^T + bh ; c_all = enc @ Wc^T + bc ----
  {
    float a0[BB], a1[BB], a2[BB], a3[BB];
    #pragma unroll
    for (int b=0;b<BB;b++){ a0[b]=0.f;a1[b]=0.f;a2[b]=0.f;a3[b]=0.f; }
    const float4* wh0 = (const float4*)(Wh + (size_t)u*DM);
    const float4* wh1 = (const float4*)(Wh + (size_t)(u+HN)*DM);
    const float4* wc0 = (const float4*)(Wc + (size_t)u*DM);
    const float4* wc1 = (const float4*)(Wc + (size_t)(u+HN)*DM);
    #pragma nounroll
    for (int kk=0; kk<DM/4; kk++){
      float4 w0=wh0[kk], w1=wh1[kk], w2=wc0[kk], w3=wc1[kk];
      #pragma unroll
      for (int b=0;b<BB;b++){
        float4 x = *(const float4*)&sh_x[b][kk*4];
        a0[b] += w0.x*x.x + w0.y*x.y + w0.z*x.z + w0.w*x.w;
        a1[b] += w1.x*x.x + w1.y*x.y + w1.z*x.z + w1.w*x.w;
        a2[b] += w2.x*x.x + w2.y*x.y + w2.z*x.z + w2.w*x.w;
        a3[b] += w3.x*x.x + w3.y*x.y + w3.z*x.z + w3.w*x.w;
      }
    }
    float bh0v = bh[u], bh1v = bh[u+HN], bc0v = bc[u], bc1v = bc[u+HN];
    #pragma unroll
    for (int b=0;b<BB;b++){
      sh_h0[b][u] = a0[b] + bh0v;
      sh_h1[b][u] = a1[b] + bh1v;
      c0r[b]      = a2[b] + bc0v;
      c1r[b]      = a3[b] + bc1v;
    }
  }
  __syncthreads();   // done reading enc from sh_x

  // ---- stage context tile ----
  {
    const float4* src = (const float4*)(ctx + (size_t)gb0*DM);
    float4* dst = (float4*)&sh_x[0][0];
    #pragma unroll
    for (int i=0;i<(BB*DM/4)/TPB;i++) dst[tid + i*TPB] = src[tid + i*TPB];
  }
  __syncthreads();

  // ---- gates_ctx = ctx @ Wih0[:,2:]^T + (b_ih0+b_hh0); also W_pos, bias1 ----
  float wposr[4][2]; float bias1r[4];
  {
    float a[4][BB];
    #pragma unroll
    for (int g=0;g<4;g++){
      #pragma unroll
      for (int b=0;b<BB;b++) a[g][b]=0.f;
    }
    const float2* wr[4];
    #pragma unroll
    for (int g=0;g<4;g++){
      const float* row = Wih0 + (size_t)(u + (g<<8))*130;
      wposr[g][0]=row[0]; wposr[g][1]=row[1];
      wr[g] = (const float2*)(row + 2);
    }
    #pragma nounroll
    for (int kk=0; kk<DM/2; kk++){
      float2 w0=wr[0][kk], w1=wr[1][kk], w2=wr[2][kk], w3=wr[3][kk];
      #pragma unroll
      for (int b=0;b<BB;b++){
        float2 x = *(const float2*)&sh_x[b][kk*2];
        a[0][b] += w0.x*x.x + w0.y*x.y;
        a[1][b] += w1.x*x.x + w1.y*x.y;
        a[2][b] += w2.x*x.x + w2.y*x.y;
        a[3][b] += w3.x*x.x + w3.y*x.y;
      }
    }
    #pragma unroll
    for (int g=0;g<4;g++){
      int j = u + (g<<8);
      float b0 = bih0[j] + bhh0[j];
      bias1r[g] = bih1[j] + bhh1[j];
      #pragma unroll
      for (int b=0;b<BB;b++) sh_gctx[b][j] = a[g][b] + b0;
    }
  }

  // ---- head constants ----
  const int m  = tid & 63;
  const int wv = tid >> 6;
  float bp1m = bp1[m];
  float w20  = Wp2[m];
  float w21  = Wp2[64 + m];
  float bp20 = bp2[0], bp21 = bp2[1];
  const float4* wp1r = (const float4*)(Wp1 + (size_t)m*HN);

  // ---- recurrent weight row pointers ----
  const float4* whh0r[4]; const float4* wih1r[4]; const float4* whh1r[4];
  #pragma unroll
  for (int g=0;g<4;g++){
    whh0r[g] = (const float4*)(Whh0 + (size_t)(u+(g<<8))*HN);
    wih1r[g] = (const float4*)(Wih1 + (size_t)(u+(g<<8))*HN);
    whh1r[g] = (const float4*)(Whh1 + (size_t)(u+(g<<8))*HN);
  }

  __syncthreads();

  // ================= 45-step rollout =================
  #pragma nounroll
  for (int t=0; t<NSTEP; t++){
    float acc[4][BB];

    // gates0 = gates_ctx + pos @ Wpos^T + h0 @ Whh0^T
    #pragma unroll
    for (int b=0;b<BB;b++){
      float p0 = sh_pos[b][0], p1 = sh_pos[b][1];
      #pragma unroll
      for (int g=0;g<4;g++)
        acc[g][b] = sh_gctx[b][u+(g<<8)] + p0*wposr[g][0] + p1*wposr[g][1];
    }
    MATVEC(whh0r, sh_h0);
    __syncthreads();                 // all reads of old sh_h0 complete

    // layer0 cell update (register-local)
    float hnew[BB];
    #pragma unroll
    for (int b=0;b<BB;b++){
      float iv = sigm(acc[0][b]);
      float fv = sigm(acc[1][b]);
      float gv = tanhx(acc[2][b]);
      float ov = sigm(acc[3][b]);
      float c  = fv*c0r[b] + iv*gv;
      c0r[b]   = c;
      hnew[b]  = ov * tanhx(c);
    }
    #pragma unroll
    for (int b=0;b<BB;b++) sh_h0[b][u] = hnew[b];
    __syncthreads();                 // new h0 visible

    // gates1 = bias1 + h0_new @ Wih1^T + h1 @ Whh1^T
    #pragma unroll
    for (int b=0;b<BB;b++){
      #pragma unroll
      for (int g=0;g<4;g++) acc[g][b] = bias1r[g];
    }
    MATVEC(wih1r, sh_h0);
    MATVEC(whh1r, sh_h1);
    __syncthreads();                 // all reads of old sh_h1 complete

    // layer1 cell update
    #pragma unroll
    for (int b=0;b<BB;b++){
      float iv = sigm(acc[0][b]);
      float fv = sigm(acc[1][b]);
      float gv = tanhx(acc[2][b]);
      float ov = sigm(acc[3][b]);
      float c  = fv*c1r[b] + iv*gv;
      c1r[b]   = c;
      hnew[b]  = ov * tanhx(c);
    }
    #pragma unroll
    for (int b=0;b<BB;b++) sh_h1[b][u] = hnew[b];
    __syncthreads();                 // new h1 visible

    // head: delta = relu(h1 @ Wp1^T + bp1) @ Wp2^T + bp2 ; pos += delta
    {
      float hp[4];
      #pragma unroll
      for (int i=0;i<4;i++) hp[i] = bp1m;
      #pragma nounroll
      for (int kk=0; kk<HN/4; kk++){
        float4 w = wp1r[kk];
        #pragma unroll
        for (int i=0;i<4;i++){
          float4 hv = *(const float4*)&sh_h1[wv*4+i][kk*4];
          hp[i] += w.x*hv.x + w.y*hv.y + w.z*hv.z + w.w*hv.w;
        }
      }
      #pragma unroll
      for (int i=0;i<4;i++){
        float p  = fmaxf(hp[i], 0.f);
        float s0 = p*w20, s1 = p*w21;
        #pragma unroll
        for (int off=32; off>0; off>>=1){
          s0 += __shfl_xor(s0, off, 64);
          s1 += __shfl_xor(s1, off, 64);
        }
        if (m == 0){
          int b = wv*4 + i;
          float np0 = sh_pos[b][0] + s0 + bp20;
          float np1 = sh_pos[b][1] + s1 + bp21;
          sh_pos[b][0]=np0; sh_pos[b][1]=np1;
          float* o = out + ((size_t)(gb0+b)*NSTEP + t)*2;
          o[0]=np0; o[1]=np1;
        }
      }
    }
    __syncthreads();                 // pos + h states settled for next step
  }
}

extern "C" void kernel_launch(void* const* d_in, const int* in_sizes, int n_in,
                              void* d_out, int out_size, void* d_ws, size_t ws_size,
                              hipStream_t stream) {
  const float* enc  = (const float*)d_in[0];
  const float* pos0 = (const float*)d_in[1];
  const float* ctx  = (const float*)d_in[2];
  const float* Wh   = (const float*)d_in[3];
  const float* bh   = (const float*)d_in[4];
  const float* Wc   = (const float*)d_in[5];
  const float* bc   = (const float*)d_in[6];
  const float* Wih0 = (const float*)d_in[7];
  const float* Whh0 = (const float*)d_in[8];
  const float* bih0 = (const float*)d_in[9];
  const float* bhh0 = (const float*)d_in[10];
  const float* Wih1 = (const float*)d_in[11];
  const float* Whh1 = (const float*)d_in[12];
  const float* bih1 = (const float*)d_in[13];
  const float* bhh1 = (const float*)d_in[14];
  const float* Wp1  = (const float*)d_in[15];
  const float* bp1  = (const float*)d_in[16];
  const float* Wp2  = (const float*)d_in[17];
  const float* bp2  = (const float*)d_in[18];
  float* out = (float*)d_out;

  const int B = 4096;
  dim3 grid(B / BB), block(TPB);
  hipLaunchKernelGGL(traj_kernel, grid, block, 0, stream,
                     enc, pos0, ctx, Wh, bh, Wc, bc, Wih0, Whh0, bih0, bhh0,
                     Wih1, Whh1, bih1, bhh1, Wp1, bp1, Wp2, bp2, out);
}